// Round 1
// baseline (4506.687 us; speedup 1.0000x reference)
//
#include <hip/hip_runtime.h>
#include <hip/hip_bf16.h>
#include <math.h>

typedef __hip_bfloat16 bf16;

#define BATCH   8192
#define NTOT    65536      // 8 chunks * BATCH
#define HID     128

__device__ __forceinline__ float b2f(bf16 v){ return __bfloat162float(v); }
__device__ __forceinline__ bf16  f2b(float v){ return __float2bfloat16(v); }
__device__ __forceinline__ float sigf(float x){ return 1.0f/(1.0f+__expf(-x)); }
__device__ __forceinline__ float tanhfast(float x){
  // tanh(x) = 1 - 2/(exp(2x)+1); saturates correctly for |x| large
  return 1.0f - 2.0f/(__expf(2.0f*x)+1.0f);
}

// ---------------------------------------------------------------------------
// K1: STFT + magnitude.  One block per batch row b. 32 windows (8 chunks x 4
// frames) staged into LDS (stride 268: 12 mod 32 -> 4-way conflict on b128,
// acceptable). Thread computes 4 bins x 2 windows, fp32 accumulate.
// mag layout: [129 bins][4 frames][NTOT], bf16.
// ---------------------------------------------------------------------------
__global__ __launch_bounds__(256) void k_stft(
    const float* __restrict__ audio, const float* __restrict__ W,
    bf16* __restrict__ mag)
{
  __shared__ float win[32*268];
  const int b   = blockIdx.x;
  const int tid = threadIdx.x;
  const float* row = audio + (size_t)b*4160;
  // stage windows: chunk i covers audio[b, 512i .. 512i+576); reflect-pad 64
  // left (xp[j]=x[64-j] for j<64); right pad unused (frame 3 ends at xp[639]).
  #pragma unroll
  for (int w = 0; w < 32; ++w){
    const int i = w >> 2, t = w & 3;
    const int m = (t == 0) ? ((tid < 64) ? (64 - tid) : (tid - 64))
                           : (t*128 - 64 + tid);
    win[w*268 + tid] = row[512*i + m];
  }
  __syncthreads();
  for (int o2 = tid; o2 < 33*16; o2 += 256){
    const int k4 = o2 >> 4;          // bin quad 0..32 (132 >= 129, clamp)
    const int wp = o2 & 15;          // windows wp and wp+16
    float ar[4][2], ai[4][2];
    #pragma unroll
    for (int kk = 0; kk < 4; ++kk){ ar[kk][0]=ar[kk][1]=0.f; ai[kk][0]=ai[kk][1]=0.f; }
    int kc[4];
    #pragma unroll
    for (int kk = 0; kk < 4; ++kk){ int k = k4*4+kk; kc[kk] = (k < 129) ? k : 128; }
    const float4* w0p = (const float4*)(win + wp*268);
    const float4* w1p = (const float4*)(win + (wp+16)*268);
    for (int u4 = 0; u4 < 64; ++u4){
      const float4 v0 = w0p[u4];
      const float4 v1 = w1p[u4];
      #pragma unroll
      for (int kk = 0; kk < 4; ++kk){
        const float4 wr = *(const float4*)(W + kc[kk]*256        + u4*4);
        const float4 wi = *(const float4*)(W + (kc[kk]+129)*256  + u4*4);
        ar[kk][0] += wr.x*v0.x + wr.y*v0.y + wr.z*v0.z + wr.w*v0.w;
        ai[kk][0] += wi.x*v0.x + wi.y*v0.y + wi.z*v0.z + wi.w*v0.w;
        ar[kk][1] += wr.x*v1.x + wr.y*v1.y + wr.z*v1.z + wr.w*v1.w;
        ai[kk][1] += wi.x*v1.x + wi.y*v1.y + wi.z*v1.z + wi.w*v1.w;
      }
    }
    #pragma unroll
    for (int kk = 0; kk < 4; ++kk){
      const int k = k4*4+kk;
      if (k < 129){
        #pragma unroll
        for (int h = 0; h < 2; ++h){
          const int w = wp + 16*h;
          const int i = w >> 2, t = w & 3;
          const float m = sqrtf(ar[kk][h]*ar[kk][h] + ai[kk][h]*ai[kk][h]);
          mag[(size_t)(k*4 + t)*NTOT + i*BATCH + b] = f2b(m);
        }
      }
    }
  }
}

// ---------------------------------------------------------------------------
// K2: enc1 conv (129->128 ch, k=3, stride 1, pad 1) + ReLU.
// Thread = (cout quad c4, chunk n); weight reads wave-uniform, act coalesced.
// ---------------------------------------------------------------------------
__global__ __launch_bounds__(256) void k_enc1(
    const bf16* __restrict__ mag, const float* __restrict__ w1,
    const float* __restrict__ b1, bf16* __restrict__ h1)
{
  const int idx = blockIdx.x*256 + threadIdx.x;
  const int n  = idx & (NTOT-1);
  const int c4 = idx >> 16;            // 0..31
  float acc[4][4];
  #pragma unroll
  for (int kk = 0; kk < 4; ++kk){
    const float bv = b1[c4*4+kk];
    #pragma unroll
    for (int t = 0; t < 4; ++t) acc[kk][t] = bv;
  }
  for (int cin = 0; cin < 129; ++cin){
    const float m0 = b2f(mag[(size_t)(cin*4+0)*NTOT + n]);
    const float m1 = b2f(mag[(size_t)(cin*4+1)*NTOT + n]);
    const float m2 = b2f(mag[(size_t)(cin*4+2)*NTOT + n]);
    const float m3 = b2f(mag[(size_t)(cin*4+3)*NTOT + n]);
    #pragma unroll
    for (int kk = 0; kk < 4; ++kk){
      const float* wp = w1 + ((size_t)(c4*4+kk)*129 + cin)*3;
      const float w0 = wp[0], wv1 = wp[1], w2 = wp[2];
      acc[kk][0] += wv1*m0 + w2*m1;
      acc[kk][1] += w0*m0 + wv1*m1 + w2*m2;
      acc[kk][2] += w0*m1 + wv1*m2 + w2*m3;
      acc[kk][3] += w0*m2 + wv1*m3;
    }
  }
  #pragma unroll
  for (int kk = 0; kk < 4; ++kk)
    #pragma unroll
    for (int t = 0; t < 4; ++t){
      float v = acc[kk][t]; v = v > 0.f ? v : 0.f;
      h1[(size_t)((c4*4+kk)*4+t)*NTOT + n] = f2b(v);
    }
}

// K3: enc2 (128->64, k=3, stride 2, pad 1) + ReLU. out frames 2.
__global__ __launch_bounds__(256) void k_enc2(
    const bf16* __restrict__ h1, const float* __restrict__ w2,
    const float* __restrict__ b2v, bf16* __restrict__ h2)
{
  const int idx = blockIdx.x*256 + threadIdx.x;
  const int n  = idx & (NTOT-1);
  const int c4 = idx >> 16;            // 0..15
  float acc[4][2];
  #pragma unroll
  for (int kk = 0; kk < 4; ++kk){ const float bv = b2v[c4*4+kk]; acc[kk][0]=bv; acc[kk][1]=bv; }
  for (int cin = 0; cin < 128; ++cin){
    const float m0 = b2f(h1[(size_t)(cin*4+0)*NTOT + n]);
    const float m1 = b2f(h1[(size_t)(cin*4+1)*NTOT + n]);
    const float m2 = b2f(h1[(size_t)(cin*4+2)*NTOT + n]);
    const float m3 = b2f(h1[(size_t)(cin*4+3)*NTOT + n]);
    #pragma unroll
    for (int kk = 0; kk < 4; ++kk){
      const float* wp = w2 + ((size_t)(c4*4+kk)*128 + cin)*3;
      acc[kk][0] += wp[1]*m0 + wp[2]*m1;                 // t'=0: in -1,0,1
      acc[kk][1] += wp[0]*m1 + wp[1]*m2 + wp[2]*m3;      // t'=1: in 1,2,3
    }
  }
  #pragma unroll
  for (int kk = 0; kk < 4; ++kk)
    #pragma unroll
    for (int t = 0; t < 2; ++t){
      float v = acc[kk][t]; v = v > 0.f ? v : 0.f;
      h2[(size_t)((c4*4+kk)*2+t)*NTOT + n] = f2b(v);
    }
}

// K4: enc3 (64->64, k=3, stride 2, pad 1) + ReLU. out frames 1 (taps in[0],in[1]).
__global__ __launch_bounds__(256) void k_enc3(
    const bf16* __restrict__ h2, const float* __restrict__ w3,
    const float* __restrict__ b3v, bf16* __restrict__ h3)
{
  const int idx = blockIdx.x*256 + threadIdx.x;
  const int n  = idx & (NTOT-1);
  const int c4 = idx >> 16;            // 0..15
  float acc[4];
  #pragma unroll
  for (int kk = 0; kk < 4; ++kk) acc[kk] = b3v[c4*4+kk];
  for (int cin = 0; cin < 64; ++cin){
    const float m0 = b2f(h2[(size_t)(cin*2+0)*NTOT + n]);
    const float m1 = b2f(h2[(size_t)(cin*2+1)*NTOT + n]);
    #pragma unroll
    for (int kk = 0; kk < 4; ++kk){
      const float* wp = w3 + ((size_t)(c4*4+kk)*64 + cin)*3;
      acc[kk] += wp[1]*m0 + wp[2]*m1;
    }
  }
  #pragma unroll
  for (int kk = 0; kk < 4; ++kk){
    float v = acc[kk]; v = v > 0.f ? v : 0.f;
    h3[(size_t)(c4*4+kk)*NTOT + n] = f2b(v);
  }
}

// K5: enc4 (64->128, k=3, stride 1, pad 1, L=1 -> only center tap) + ReLU.
__global__ __launch_bounds__(256) void k_enc4(
    const bf16* __restrict__ h3, const float* __restrict__ w4,
    const float* __restrict__ b4v, bf16* __restrict__ h4)
{
  const int idx = blockIdx.x*256 + threadIdx.x;
  const int n  = idx & (NTOT-1);
  const int c4 = idx >> 16;            // 0..31
  float acc[4];
  #pragma unroll
  for (int kk = 0; kk < 4; ++kk) acc[kk] = b4v[c4*4+kk];
  for (int cin = 0; cin < 64; ++cin){
    const float m = b2f(h3[(size_t)cin*NTOT + n]);
    #pragma unroll
    for (int kk = 0; kk < 4; ++kk)
      acc[kk] += w4[((size_t)(c4*4+kk)*64 + cin)*3 + 1] * m;
  }
  #pragma unroll
  for (int kk = 0; kk < 4; ++kk){
    float v = acc[kk]; v = v > 0.f ? v : 0.f;
    h4[(size_t)(c4*4+kk)*NTOT + n] = f2b(v);
  }
}

// K6: transpose h0/c0 [B,128] -> [128][B]
__global__ __launch_bounds__(256) void k_init(
    const float* __restrict__ h0, const float* __restrict__ c0,
    float* __restrict__ hT0, float* __restrict__ cT)
{
  const int idx = blockIdx.x*256 + threadIdx.x;   // 1M
  const int b = idx >> 7, c = idx & 127;
  hT0[c*BATCH + b] = h0[idx];
  cT [c*BATCH + b] = c0[idx];
}

// K7: one LSTM step. Thread = (unit c, batch b). Computes both x- and h-GEMV
// contributions (w reads wave-uniform, acts coalesced), then pointwise update.
__global__ __launch_bounds__(256) void k_lstm(
    const bf16* __restrict__ h4, const float* __restrict__ wih,
    const float* __restrict__ whh, const float* __restrict__ bih,
    const float* __restrict__ bhh, const float* __restrict__ hprev,
    float* __restrict__ hout, float* __restrict__ cT, int step)
{
  const int idx = blockIdx.x*256 + threadIdx.x;   // 1M
  const int b = idx & (BATCH-1);
  const int c = idx >> 13;                        // 0..127
  float a0 = bih[c]       + bhh[c];
  float a1 = bih[128 + c] + bhh[128 + c];
  float a2 = bih[256 + c] + bhh[256 + c];
  float a3 = bih[384 + c] + bhh[384 + c];
  for (int cp = 0; cp < 128; ++cp){
    const float hv = hprev[cp*BATCH + b];
    const float fv = b2f(h4[(size_t)cp*NTOT + step*BATCH + b]);
    a0 += wih[(0*128+c)*128 + cp]*fv + whh[(0*128+c)*128 + cp]*hv;
    a1 += wih[(1*128+c)*128 + cp]*fv + whh[(1*128+c)*128 + cp]*hv;
    a2 += wih[(2*128+c)*128 + cp]*fv + whh[(2*128+c)*128 + cp]*hv;
    a3 += wih[(3*128+c)*128 + cp]*fv + whh[(3*128+c)*128 + cp]*hv;
  }
  const float co = cT[c*BATCH + b];
  const float ig = sigf(a0), fg = sigf(a1), gg = tanhfast(a2), og = sigf(a3);
  const float cn = fg*co + ig*gg;
  const float hn = og*tanhfast(cn);
  cT  [c*BATCH + b] = cn;
  hout[c*BATCH + b] = hn;
}

// K8: per-batch head: p_s = sigmoid(h_s . out_w + out_b); final = 1-prod(1-p)
__global__ __launch_bounds__(256) void k_head(
    const float* __restrict__ hseq, const float* __restrict__ ow,
    const float* __restrict__ ob, float* __restrict__ outp)
{
  const int b = blockIdx.x*256 + threadIdx.x;     // 8192
  float prod = 1.f;
  for (int s = 0; s < 8; ++s){
    float acc = ob[0];
    const float* hp = hseq + (size_t)s*HID*BATCH;
    for (int c = 0; c < 128; ++c) acc += ow[c]*hp[c*BATCH + b];
    prod *= (1.f - sigf(acc));
  }
  outp[b] = 1.f - prod;
}

// K9: transpose h_fin, c_fin to [B,128] row-major in d_out
__global__ __launch_bounds__(256) void k_outT(
    const float* __restrict__ h7, const float* __restrict__ cT,
    float* __restrict__ out)
{
  const int idx = blockIdx.x*256 + threadIdx.x;   // 1M
  const int b = idx >> 7, c = idx & 127;
  out[8192 + idx]           = h7[c*BATCH + b];
  out[8192 + 1048576 + idx] = cT[c*BATCH + b];
}

// ---------------------------------------------------------------------------
extern "C" void kernel_launch(void* const* d_in, const int* in_sizes, int n_in,
                              void* d_out, int out_size, void* d_ws, size_t ws_size,
                              hipStream_t stream)
{
  (void)in_sizes; (void)n_in; (void)out_size; (void)ws_size;
  const float* audio = (const float*)d_in[0];
  const float* h0    = (const float*)d_in[1];
  const float* c0    = (const float*)d_in[2];
  const float* stftw = (const float*)d_in[3];
  const float* w1 = (const float*)d_in[4];  const float* b1 = (const float*)d_in[5];
  const float* w2 = (const float*)d_in[6];  const float* b2 = (const float*)d_in[7];
  const float* w3 = (const float*)d_in[8];  const float* b3 = (const float*)d_in[9];
  const float* w4 = (const float*)d_in[10]; const float* b4 = (const float*)d_in[11];
  const float* wih = (const float*)d_in[12]; const float* whh = (const float*)d_in[13];
  const float* bih = (const float*)d_in[14]; const float* bhh = (const float*)d_in[15];
  const float* ow  = (const float*)d_in[16]; const float* ob  = (const float*)d_in[17];
  float* out = (float*)d_out;

  // workspace regions (bytes). R0 holds mag (K1->K2), then is reused.
  char* ws = (char*)d_ws;
  bf16*  mag  = (bf16*) (ws + 0);          // 129*4*65536 bf16 = 67,633,152 B
  bf16*  h3   = (bf16*) (ws + 0);          //  64*65536   bf16 (after mag dead)
  bf16*  h4   = (bf16*) (ws + 8388608);    // 128*65536   bf16
  float* hT0  = (float*)(ws + 25165824);   // 128*8192    f32
  float* cT   = (float*)(ws + 29360128);   // 128*8192    f32
  float* hseq = (float*)(ws + 33554432);   // 8*128*8192  f32 (ends 67,108,864)
  bf16*  h1   = (bf16*) (ws + 67633152);   // 128*4*65536 bf16
  bf16*  h2   = (bf16*) (ws + 134742016);  //  64*2*65536 bf16 (ends 151,519,232)

  k_stft<<<8192, 256, 0, stream>>>(audio, stftw, mag);
  k_enc1<<<8192, 256, 0, stream>>>(mag, w1, b1, h1);
  k_enc2<<<4096, 256, 0, stream>>>(h1, w2, b2, h2);
  k_enc3<<<4096, 256, 0, stream>>>(h2, w3, b3, h3);
  k_enc4<<<8192, 256, 0, stream>>>(h3, w4, b4, h4);
  k_init<<<4096, 256, 0, stream>>>(h0, c0, hT0, cT);
  for (int s = 0; s < 8; ++s){
    const float* hprev = (s == 0) ? hT0 : (hseq + (size_t)(s-1)*HID*BATCH);
    k_lstm<<<4096, 256, 0, stream>>>(h4, wih, whh, bih, bhh, hprev,
                                     hseq + (size_t)s*HID*BATCH, cT, s);
  }
  k_head<<<32, 256, 0, stream>>>(hseq, ow, ob, out);
  k_outT<<<4096, 256, 0, stream>>>(hseq + (size_t)7*HID*BATCH, cT, out);
}

// Round 2
// 3565.286 us; speedup vs baseline: 1.2640x; 1.2640x over previous
//
#include <hip/hip_runtime.h>
#include <hip/hip_bf16.h>
#include <math.h>

typedef __hip_bfloat16 bf16;
typedef __attribute__((ext_vector_type(4))) float f32x4;
typedef __attribute__((ext_vector_type(8))) short short8;
typedef __attribute__((ext_vector_type(4))) short short4v;

#define BATCH   8192
#define NTOT    65536      // 8 chunks * BATCH
#define NW      262144     // total windows = 8 chunks * 4 frames * BATCH
#define HID     128

__device__ __forceinline__ float b2f(bf16 v){ return __bfloat162float(v); }
__device__ __forceinline__ bf16  f2b(float v){ return __float2bfloat16(v); }
__device__ __forceinline__ short f2bs(float v){
  bf16 b = __float2bfloat16(v);
  return *reinterpret_cast<short*>(&b);
}
__device__ __forceinline__ float s2f(short s){
  unsigned int u = ((unsigned int)(unsigned short)s) << 16;
  return __uint_as_float(u);
}
__device__ __forceinline__ float sigf(float x){ return 1.0f/(1.0f+__expf(-x)); }
__device__ __forceinline__ float tanhfast(float x){
  return 1.0f - 2.0f/(__expf(2.0f*x)+1.0f);
}

// ---------------------------------------------------------------------------
// K0: convert STFT weights fp32 -> bf16 ([258][256])
// ---------------------------------------------------------------------------
__global__ __launch_bounds__(256) void k_wcvt(
    const float* __restrict__ W, bf16* __restrict__ Wb)
{
  const int idx = blockIdx.x*256 + threadIdx.x;
  if (idx < 258*256) Wb[idx] = f2b(W[idx]);
}

// ---------------------------------------------------------------------------
// K1: STFT as bf16 MFMA GEMM, magnitude fused.
// Block: 32 bins (mgrp) x 128 windows (= chunk i, 32 batch rows, 4 frames).
// Stages xp[32][640] bf16 (reflect-padded chunks) in LDS, XOR-swizzled.
// Wave wq: windows wq*32..wq*32+31 (rows wq*8..wq*8+7 of xp, wave-private).
// mag layout: [129][NW], n2 = i*32768 + b*4 + t.
// ---------------------------------------------------------------------------
__global__ __launch_bounds__(256) void k_stft_gemm(
    const float* __restrict__ audio, const bf16* __restrict__ Wb,
    bf16* __restrict__ mag)
{
  __shared__ __align__(16) char xp[32*1280];
  const int tid  = threadIdx.x;
  const int lane = tid & 63;
  const int wq   = tid >> 6;
  const int mgrp = blockIdx.x >> 11;      // 0..4
  const int tile = blockIdx.x & 2047;
  const int i    = tile >> 8;             // chunk 0..7
  const int b0   = (tile & 255) * 32;     // batch base
  const int bin0 = mgrp * 32;

  // ---- stage 8 chunk-rows (wave-private; no barrier needed) ----
  const float* abase = audio + (size_t)(b0 + wq*8) * 4160 + i * 512;
  for (int r = 0; r < 8; ++r){
    const float* arow = abase + (size_t)r * 4160;
    const int rowb = (wq*8 + r) * 1280;
    for (int c = lane; c < 144; c += 64){        // xp[64 + 4c .. +3] = x[4c..4c+3]
      const float4 v = *(const float4*)(arow + c*4);
      short4v s;
      s.x = f2bs(v.x); s.y = f2bs(v.y); s.z = f2bs(v.z); s.w = f2bs(v.w);
      int off = rowb + 128 + c*8;
      off ^= ((off>>8)&7)<<4;
      *(short4v*)(xp + off) = s;
    }
    { // reflect: xp[j] = x[64-j], j = 0..63
      const float v = arow[64 - lane];
      int off = rowb + lane*2;
      off ^= ((off>>8)&7)<<4;
      *(short*)(xp + off) = f2bs(v);
    }
  }

  // ---- per-lane addresses ----
  int bbase[2];
  #pragma unroll
  for (int ng = 0; ng < 2; ++ng){
    const int wl = wq*32 + ng*16 + (lane & 15);  // window-local 0..127
    const int bl = wl >> 2, tt = wl & 3;
    bbase[ng] = bl*1280 + tt*256 + (lane>>4)*16; // bytes, pre-swizzle
  }
  int arow_off[2][2];                            // [re/im][mg] byte offsets in Wb
  #pragma unroll
  for (int mg = 0; mg < 2; ++mg){
    int bin = bin0 + mg*16 + (lane & 15);
    if (bin > 128) bin = 128;                    // clamp (garbage rows not stored)
    arow_off[0][mg] = bin * 512;
    arow_off[1][mg] = (bin + 129) * 512;
  }
  const int kgo = (lane>>4)*16;                  // k-chunk byte offset

  f32x4 zero = {0.f, 0.f, 0.f, 0.f};
  f32x4 accRe[2][2], accIm[2][2];
  #pragma unroll
  for (int mg = 0; mg < 2; ++mg)
    #pragma unroll
    for (int ng = 0; ng < 2; ++ng){ accRe[mg][ng] = zero; accIm[mg][ng] = zero; }

  // ---- K loop: 256 taps in 2 halves of 4 k-steps (A held in registers) ----
  #pragma unroll
  for (int half = 0; half < 2; ++half){
    short8 aRe[2][4], aIm[2][4];
    #pragma unroll
    for (int ks4 = 0; ks4 < 4; ++ks4){
      const int kb = (half*4 + ks4)*64 + kgo;
      #pragma unroll
      for (int mg = 0; mg < 2; ++mg){
        aRe[mg][ks4] = *(const short8*)((const char*)Wb + arow_off[0][mg] + kb);
        aIm[mg][ks4] = *(const short8*)((const char*)Wb + arow_off[1][mg] + kb);
      }
    }
    #pragma unroll
    for (int ks4 = 0; ks4 < 4; ++ks4){
      const int kb = (half*4 + ks4)*64;
      short8 bfr[2];
      #pragma unroll
      for (int ng = 0; ng < 2; ++ng){
        int off = bbase[ng] + kb;
        off ^= ((off>>8)&7)<<4;
        bfr[ng] = *(const short8*)(xp + off);
      }
      #pragma unroll
      for (int mg = 0; mg < 2; ++mg)
        #pragma unroll
        for (int ng = 0; ng < 2; ++ng){
          accRe[mg][ng] = __builtin_amdgcn_mfma_f32_16x16x32_bf16(
              aRe[mg][ks4], bfr[ng], accRe[mg][ng], 0, 0, 0);
          accIm[mg][ng] = __builtin_amdgcn_mfma_f32_16x16x32_bf16(
              aIm[mg][ks4], bfr[ng], accIm[mg][ng], 0, 0, 0);
        }
    }
  }

  // ---- epilogue: magnitude + store ----
  const size_t n2base = (size_t)i*32768 + (size_t)b0*4 + wq*32;
  #pragma unroll
  for (int mg = 0; mg < 2; ++mg)
    #pragma unroll
    for (int j = 0; j < 4; ++j){
      const int bin = bin0 + mg*16 + (lane>>4)*4 + j;
      if (bin <= 128){
        #pragma unroll
        for (int ng = 0; ng < 2; ++ng){
          const float re = accRe[mg][ng][j], im = accIm[mg][ng][j];
          mag[(size_t)bin*NW + n2base + ng*16 + (lane&15)] =
              f2b(sqrtf(re*re + im*im));
        }
      }
    }
}

// ---------------------------------------------------------------------------
// K2: enc1 conv (129->128 ch, k=3, stride 1, pad 1) + ReLU.
// mag layout [129][NW]: 4 frames of (i,b) are contiguous -> one 8B load.
// ---------------------------------------------------------------------------
__global__ __launch_bounds__(256) void k_enc1(
    const bf16* __restrict__ mag, const float* __restrict__ w1,
    const float* __restrict__ b1, bf16* __restrict__ h1)
{
  const int idx = blockIdx.x*256 + threadIdx.x;
  const int n  = idx & (NTOT-1);
  const int c4 = idx >> 16;            // 0..31
  const int i = n >> 13, b = n & (BATCH-1);
  const size_t mbase = (size_t)i*32768 + (size_t)b*4;
  float acc[4][4];
  #pragma unroll
  for (int kk = 0; kk < 4; ++kk){
    const float bv = b1[c4*4+kk];
    #pragma unroll
    for (int t = 0; t < 4; ++t) acc[kk][t] = bv;
  }
  for (int cin = 0; cin < 129; ++cin){
    const short4v mv = *(const short4v*)(mag + (size_t)cin*NW + mbase);
    const float m0 = s2f(mv.x), m1 = s2f(mv.y), m2 = s2f(mv.z), m3 = s2f(mv.w);
    #pragma unroll
    for (int kk = 0; kk < 4; ++kk){
      const float* wp = w1 + ((size_t)(c4*4+kk)*129 + cin)*3;
      const float w0 = wp[0], wv1 = wp[1], w2 = wp[2];
      acc[kk][0] += wv1*m0 + w2*m1;
      acc[kk][1] += w0*m0 + wv1*m1 + w2*m2;
      acc[kk][2] += w0*m1 + wv1*m2 + w2*m3;
      acc[kk][3] += w0*m2 + wv1*m3;
    }
  }
  #pragma unroll
  for (int kk = 0; kk < 4; ++kk)
    #pragma unroll
    for (int t = 0; t < 4; ++t){
      float v = acc[kk][t]; v = v > 0.f ? v : 0.f;
      h1[(size_t)((c4*4+kk)*4+t)*NTOT + n] = f2b(v);
    }
}

// K3: enc2 (128->64, k=3, stride 2, pad 1) + ReLU. out frames 2.
__global__ __launch_bounds__(256) void k_enc2(
    const bf16* __restrict__ h1, const float* __restrict__ w2,
    const float* __restrict__ b2v, bf16* __restrict__ h2)
{
  const int idx = blockIdx.x*256 + threadIdx.x;
  const int n  = idx & (NTOT-1);
  const int c4 = idx >> 16;            // 0..15
  float acc[4][2];
  #pragma unroll
  for (int kk = 0; kk < 4; ++kk){ const float bv = b2v[c4*4+kk]; acc[kk][0]=bv; acc[kk][1]=bv; }
  for (int cin = 0; cin < 128; ++cin){
    const float m0 = b2f(h1[(size_t)(cin*4+0)*NTOT + n]);
    const float m1 = b2f(h1[(size_t)(cin*4+1)*NTOT + n]);
    const float m2 = b2f(h1[(size_t)(cin*4+2)*NTOT + n]);
    const float m3 = b2f(h1[(size_t)(cin*4+3)*NTOT + n]);
    #pragma unroll
    for (int kk = 0; kk < 4; ++kk){
      const float* wp = w2 + ((size_t)(c4*4+kk)*128 + cin)*3;
      acc[kk][0] += wp[1]*m0 + wp[2]*m1;
      acc[kk][1] += wp[0]*m1 + wp[1]*m2 + wp[2]*m3;
    }
  }
  #pragma unroll
  for (int kk = 0; kk < 4; ++kk)
    #pragma unroll
    for (int t = 0; t < 2; ++t){
      float v = acc[kk][t]; v = v > 0.f ? v : 0.f;
      h2[(size_t)((c4*4+kk)*2+t)*NTOT + n] = f2b(v);
    }
}

// K4: enc3 (64->64, k=3, stride 2, pad 1) + ReLU. out frames 1.
__global__ __launch_bounds__(256) void k_enc3(
    const bf16* __restrict__ h2, const float* __restrict__ w3,
    const float* __restrict__ b3v, bf16* __restrict__ h3)
{
  const int idx = blockIdx.x*256 + threadIdx.x;
  const int n  = idx & (NTOT-1);
  const int c4 = idx >> 16;            // 0..15
  float acc[4];
  #pragma unroll
  for (int kk = 0; kk < 4; ++kk) acc[kk] = b3v[c4*4+kk];
  for (int cin = 0; cin < 64; ++cin){
    const float m0 = b2f(h2[(size_t)(cin*2+0)*NTOT + n]);
    const float m1 = b2f(h2[(size_t)(cin*2+1)*NTOT + n]);
    #pragma unroll
    for (int kk = 0; kk < 4; ++kk){
      const float* wp = w3 + ((size_t)(c4*4+kk)*64 + cin)*3;
      acc[kk] += wp[1]*m0 + wp[2]*m1;
    }
  }
  #pragma unroll
  for (int kk = 0; kk < 4; ++kk){
    float v = acc[kk]; v = v > 0.f ? v : 0.f;
    h3[(size_t)(c4*4+kk)*NTOT + n] = f2b(v);
  }
}

// K5: enc4 (64->128, k=3, stride 1, pad 1, L=1 -> center tap) + ReLU.
__global__ __launch_bounds__(256) void k_enc4(
    const bf16* __restrict__ h3, const float* __restrict__ w4,
    const float* __restrict__ b4v, bf16* __restrict__ h4)
{
  const int idx = blockIdx.x*256 + threadIdx.x;
  const int n  = idx & (NTOT-1);
  const int c4 = idx >> 16;            // 0..31
  float acc[4];
  #pragma unroll
  for (int kk = 0; kk < 4; ++kk) acc[kk] = b4v[c4*4+kk];
  for (int cin = 0; cin < 64; ++cin){
    const float m = b2f(h3[(size_t)cin*NTOT + n]);
    #pragma unroll
    for (int kk = 0; kk < 4; ++kk)
      acc[kk] += w4[((size_t)(c4*4+kk)*64 + cin)*3 + 1] * m;
  }
  #pragma unroll
  for (int kk = 0; kk < 4; ++kk){
    float v = acc[kk]; v = v > 0.f ? v : 0.f;
    h4[(size_t)(c4*4+kk)*NTOT + n] = f2b(v);
  }
}

// K6: transpose h0/c0 [B,128] -> [128][B]
__global__ __launch_bounds__(256) void k_init(
    const float* __restrict__ h0, const float* __restrict__ c0,
    float* __restrict__ hT0, float* __restrict__ cT)
{
  const int idx = blockIdx.x*256 + threadIdx.x;   // 1M
  const int b = idx >> 7, c = idx & 127;
  hT0[c*BATCH + b] = h0[idx];
  cT [c*BATCH + b] = c0[idx];
}

// K7: one LSTM step.
__global__ __launch_bounds__(256) void k_lstm(
    const bf16* __restrict__ h4, const float* __restrict__ wih,
    const float* __restrict__ whh, const float* __restrict__ bih,
    const float* __restrict__ bhh, const float* __restrict__ hprev,
    float* __restrict__ hout, float* __restrict__ cT, int step)
{
  const int idx = blockIdx.x*256 + threadIdx.x;   // 1M
  const int b = idx & (BATCH-1);
  const int c = idx >> 13;                        // 0..127
  float a0 = bih[c]       + bhh[c];
  float a1 = bih[128 + c] + bhh[128 + c];
  float a2 = bih[256 + c] + bhh[256 + c];
  float a3 = bih[384 + c] + bhh[384 + c];
  for (int cp = 0; cp < 128; ++cp){
    const float hv = hprev[cp*BATCH + b];
    const float fv = b2f(h4[(size_t)cp*NTOT + step*BATCH + b]);
    a0 += wih[(0*128+c)*128 + cp]*fv + whh[(0*128+c)*128 + cp]*hv;
    a1 += wih[(1*128+c)*128 + cp]*fv + whh[(1*128+c)*128 + cp]*hv;
    a2 += wih[(2*128+c)*128 + cp]*fv + whh[(2*128+c)*128 + cp]*hv;
    a3 += wih[(3*128+c)*128 + cp]*fv + whh[(3*128+c)*128 + cp]*hv;
  }
  const float co = cT[c*BATCH + b];
  const float ig = sigf(a0), fg = sigf(a1), gg = tanhfast(a2), og = sigf(a3);
  const float cn = fg*co + ig*gg;
  const float hn = og*tanhfast(cn);
  cT  [c*BATCH + b] = cn;
  hout[c*BATCH + b] = hn;
}

// K8: head: p_s = sigmoid(h_s . out_w + out_b); final = 1-prod(1-p)
__global__ __launch_bounds__(256) void k_head(
    const float* __restrict__ hseq, const float* __restrict__ ow,
    const float* __restrict__ ob, float* __restrict__ outp)
{
  const int b = blockIdx.x*256 + threadIdx.x;     // 8192
  float prod = 1.f;
  for (int s = 0; s < 8; ++s){
    float acc = ob[0];
    const float* hp = hseq + (size_t)s*HID*BATCH;
    for (int c = 0; c < 128; ++c) acc += ow[c]*hp[c*BATCH + b];
    prod *= (1.f - sigf(acc));
  }
  outp[b] = 1.f - prod;
}

// K9: transpose h_fin, c_fin to [B,128] in d_out
__global__ __launch_bounds__(256) void k_outT(
    const float* __restrict__ h7, const float* __restrict__ cT,
    float* __restrict__ out)
{
  const int idx = blockIdx.x*256 + threadIdx.x;   // 1M
  const int b = idx >> 7, c = idx & 127;
  out[8192 + idx]           = h7[c*BATCH + b];
  out[8192 + 1048576 + idx] = cT[c*BATCH + b];
}

// ---------------------------------------------------------------------------
extern "C" void kernel_launch(void* const* d_in, const int* in_sizes, int n_in,
                              void* d_out, int out_size, void* d_ws, size_t ws_size,
                              hipStream_t stream)
{
  (void)in_sizes; (void)n_in; (void)out_size; (void)ws_size;
  const float* audio = (const float*)d_in[0];
  const float* h0    = (const float*)d_in[1];
  const float* c0    = (const float*)d_in[2];
  const float* stftw = (const float*)d_in[3];
  const float* w1 = (const float*)d_in[4];  const float* b1 = (const float*)d_in[5];
  const float* w2 = (const float*)d_in[6];  const float* b2 = (const float*)d_in[7];
  const float* w3 = (const float*)d_in[8];  const float* b3 = (const float*)d_in[9];
  const float* w4 = (const float*)d_in[10]; const float* b4 = (const float*)d_in[11];
  const float* wih = (const float*)d_in[12]; const float* whh = (const float*)d_in[13];
  const float* bih = (const float*)d_in[14]; const float* bhh = (const float*)d_in[15];
  const float* ow  = (const float*)d_in[16]; const float* ob  = (const float*)d_in[17];
  float* out = (float*)d_out;

  // workspace regions (bytes); liveness-based aliasing:
  //   mag [0 .. 67,633,152)        live K1 -> K2
  //   Wbf [67,633,152 .. +132,096) live K0 -> K1 (inside later h1 region)
  //   h1  [67,633,152 .. 134,742,016) live K2 -> K3
  //   h2  [134,742,016 .. 151,519,232) live K3 -> K4
  //   h3  [0 .. 8,388,608)         live K4 -> K5 (inside dead mag)
  //   h4  [8,388,608 .. 25,165,824) live K5 -> LSTM
  char* ws = (char*)d_ws;
  bf16*  mag  = (bf16*) (ws + 0);
  bf16*  h3   = (bf16*) (ws + 0);
  bf16*  h4   = (bf16*) (ws + 8388608);
  float* hT0  = (float*)(ws + 25165824);
  float* cT   = (float*)(ws + 29360128);
  float* hseq = (float*)(ws + 33554432);
  bf16*  h1   = (bf16*) (ws + 67633152);
  bf16*  Wbf  = (bf16*) (ws + 67633152);
  bf16*  h2   = (bf16*) (ws + 134742016);

  k_wcvt<<<258, 256, 0, stream>>>(stftw, Wbf);
  k_stft_gemm<<<5*2048, 256, 0, stream>>>(audio, Wbf, mag);
  k_enc1<<<8192, 256, 0, stream>>>(mag, w1, b1, h1);
  k_enc2<<<4096, 256, 0, stream>>>(h1, w2, b2, h2);
  k_enc3<<<4096, 256, 0, stream>>>(h2, w3, b3, h3);
  k_enc4<<<8192, 256, 0, stream>>>(h3, w4, b4, h4);
  k_init<<<4096, 256, 0, stream>>>(h0, c0, hT0, cT);
  for (int s = 0; s < 8; ++s){
    const float* hprev = (s == 0) ? hT0 : (hseq + (size_t)(s-1)*HID*BATCH);
    k_lstm<<<4096, 256, 0, stream>>>(h4, wih, whh, bih, bhh, hprev,
                                     hseq + (size_t)s*HID*BATCH, cT, s);
  }
  k_head<<<32, 256, 0, stream>>>(hseq, ow, ob, out);
  k_outT<<<4096, 256, 0, stream>>>(hseq + (size_t)7*HID*BATCH, cT, out);
}

// Round 10
// 987.722 us; speedup vs baseline: 4.5627x; 3.6096x over previous
//
#include <hip/hip_runtime.h>
#include <hip/hip_bf16.h>
#include <math.h>

typedef __hip_bfloat16 bf16;
typedef __attribute__((ext_vector_type(4))) float f32x4;
typedef __attribute__((ext_vector_type(8))) short short8;
typedef __attribute__((ext_vector_type(4))) short short4v;

#define BATCH   8192
#define NTOT    65536      // 8 chunks * BATCH
#define NT2     131072     // 2 frames * NTOT (enc2 out)
#define NW      262144     // 8 chunks * 4 frames * BATCH
#define HID     128

__device__ __forceinline__ float b2f(bf16 v){ return __bfloat162float(v); }
__device__ __forceinline__ bf16  f2b(float v){ return __float2bfloat16(v); }
__device__ __forceinline__ short f2bs(float v){
  bf16 b = __float2bfloat16(v);
  return *reinterpret_cast<short*>(&b);
}
__device__ __forceinline__ float sigf(float x){ return 1.0f/(1.0f+__expf(-x)); }
__device__ __forceinline__ float tanhfast(float x){
  return 1.0f - 2.0f/(__expf(2.0f*x)+1.0f);
}

// ---------------------------------------------------------------------------
// Weight conversion (hi/lo split: W = hi + lo, lo = bf16(W - hi))
// ---------------------------------------------------------------------------
__global__ __launch_bounds__(256) void k_wcvt(        // stft W -> bf16 [258][256]
    const float* __restrict__ W, bf16* __restrict__ Wb)
{
  const int idx = blockIdx.x*256 + threadIdx.x;
  if (idx < 258*256) Wb[idx] = f2b(W[idx]);
}
__global__ __launch_bounds__(256) void k_w1cvt(       // w1 -> [3][128][320] hi|lo
    const float* __restrict__ w1, bf16* __restrict__ w1b)
{
  const int idx = blockIdx.x*256 + threadIdx.x;       // 3*128*320 = 122880
  if (idx >= 122880) return;
  const int dt = idx / 40960, rem = idx % 40960;
  const int cout = rem / 320, k = rem % 320;
  const int kk = (k >= 160) ? (k - 160) : k;
  const float v = (kk < 129) ? w1[(cout*129 + kk)*3 + dt] : 0.f;
  const bf16 hi = f2b(v);
  w1b[idx] = (k >= 160) ? f2b(v - b2f(hi)) : hi;
}
__global__ __launch_bounds__(256) void k_w2cvt(       // w2 -> [3][64][256] hi|lo
    const float* __restrict__ w2, bf16* __restrict__ w2b)
{
  const int idx = blockIdx.x*256 + threadIdx.x;       // 3*64*256 = 49152
  if (idx >= 49152) return;
  const int dt = idx >> 14, cout = (idx >> 8) & 63, k = idx & 255;
  const int kk = k & 127;
  const float v = w2[(cout*128 + kk)*3 + dt];
  const bf16 hi = f2b(v);
  w2b[idx] = (k >= 128) ? f2b(v - b2f(hi)) : hi;
}
// LSTM weights -> [512 rows][640]: [Whh_hi | Whh_hi | Whh_lo | Wih_hi | Wih_lo]
// pairs with B rows [h_hi; h_lo; h_hi; x; x].
__global__ __launch_bounds__(256) void k_wlcvt(
    const float* __restrict__ wih, const float* __restrict__ whh,
    bf16* __restrict__ wl)
{
  const int idx = blockIdx.x*256 + threadIdx.x;       // 512*640 = 327680
  if (idx >= 327680) return;
  const int r = idx / 640, k = idx % 640;
  const int part = k >> 7, kk = k & 127;
  const float f = (part < 3) ? whh[r*128 + kk] : wih[r*128 + kk];
  const bf16 hi = f2b(f);
  const bool lo = (part == 2) || (part == 4);
  wl[idx] = lo ? f2b(f - b2f(hi)) : hi;
}

// ---------------------------------------------------------------------------
// K1: STFT bf16 MFMA GEMM, magnitude fused, mgrp looped in-block (audio
// staged once). mag layout: [129][NW], n2 = i*32768 + b*4 + t.
// ---------------------------------------------------------------------------
__global__ __launch_bounds__(256) void k_stft_gemm(
    const float* __restrict__ audio, const bf16* __restrict__ Wb,
    bf16* __restrict__ mag)
{
  __shared__ __align__(16) char xp[32*1280];
  const int tid  = threadIdx.x;
  const int lane = tid & 63;
  const int wq   = tid >> 6;
  const int tile = blockIdx.x;            // 0..2047
  const int i    = tile >> 8;             // chunk 0..7
  const int b0   = (tile & 255) * 32;     // batch base

  const float* abase = audio + (size_t)(b0 + wq*8) * 4160 + i * 512;
  for (int r = 0; r < 8; ++r){
    const float* arow = abase + (size_t)r * 4160;
    const int rowb = (wq*8 + r) * 1280;
    for (int c = lane; c < 144; c += 64){
      const float4 v = *(const float4*)(arow + c*4);
      short4v s;
      s.x = f2bs(v.x); s.y = f2bs(v.y); s.z = f2bs(v.z); s.w = f2bs(v.w);
      int off = rowb + 128 + c*8;
      off ^= ((off>>8)&7)<<4;
      *(short4v*)(xp + off) = s;
    }
    {
      const float v = arow[64 - lane];
      int off = rowb + lane*2;
      off ^= ((off>>8)&7)<<4;
      *(short*)(xp + off) = f2bs(v);
    }
  }

  int bbase[2];
  #pragma unroll
  for (int ng = 0; ng < 2; ++ng){
    const int wl = wq*32 + ng*16 + (lane & 15);
    const int bl = wl >> 2, tt = wl & 3;
    bbase[ng] = bl*1280 + tt*256 + (lane>>4)*16;
  }
  const int kgo = (lane>>4)*16;
  const size_t n2base = (size_t)i*32768 + (size_t)b0*4 + wq*32;

  for (int mgrp = 0; mgrp < 5; ++mgrp){
    const int bin0 = mgrp * 32;
    int arow_off[2][2];
    #pragma unroll
    for (int mg = 0; mg < 2; ++mg){
      int bin = bin0 + mg*16 + (lane & 15);
      if (bin > 128) bin = 128;
      arow_off[0][mg] = bin * 512;
      arow_off[1][mg] = (bin + 129) * 512;
    }
    f32x4 zero = {0.f, 0.f, 0.f, 0.f};
    f32x4 accRe[2][2], accIm[2][2];
    #pragma unroll
    for (int mg = 0; mg < 2; ++mg)
      #pragma unroll
      for (int ng = 0; ng < 2; ++ng){ accRe[mg][ng] = zero; accIm[mg][ng] = zero; }

    #pragma unroll
    for (int half = 0; half < 2; ++half){
      short8 aRe[2][4], aIm[2][4];
      #pragma unroll
      for (int ks4 = 0; ks4 < 4; ++ks4){
        const int kb = (half*4 + ks4)*64 + kgo;
        #pragma unroll
        for (int mg = 0; mg < 2; ++mg){
          aRe[mg][ks4] = *(const short8*)((const char*)Wb + arow_off[0][mg] + kb);
          aIm[mg][ks4] = *(const short8*)((const char*)Wb + arow_off[1][mg] + kb);
        }
      }
      #pragma unroll
      for (int ks4 = 0; ks4 < 4; ++ks4){
        const int kb = (half*4 + ks4)*64;
        short8 bfr[2];
        #pragma unroll
        for (int ng = 0; ng < 2; ++ng){
          int off = bbase[ng] + kb;
          off ^= ((off>>8)&7)<<4;
          bfr[ng] = *(const short8*)(xp + off);
        }
        #pragma unroll
        for (int mg = 0; mg < 2; ++mg)
          #pragma unroll
          for (int ng = 0; ng < 2; ++ng){
            accRe[mg][ng] = __builtin_amdgcn_mfma_f32_16x16x32_bf16(
                aRe[mg][ks4], bfr[ng], accRe[mg][ng], 0, 0, 0);
            accIm[mg][ng] = __builtin_amdgcn_mfma_f32_16x16x32_bf16(
                aIm[mg][ks4], bfr[ng], accIm[mg][ng], 0, 0, 0);
          }
      }
    }
    #pragma unroll
    for (int mg = 0; mg < 2; ++mg)
      #pragma unroll
      for (int j = 0; j < 4; ++j){
        const int bin = bin0 + mg*16 + (lane>>4)*4 + j;
        if (bin <= 128){
          #pragma unroll
          for (int ng = 0; ng < 2; ++ng){
            const float re = accRe[mg][ng][j], im = accIm[mg][ng][j];
            mag[(size_t)bin*NW + n2base + ng*16 + (lane&15)] =
                f2b(sqrtf(re*re + im*im));
          }
        }
      }
  }
}

// ---------------------------------------------------------------------------
// K2: enc1 MFMA GEMM hi/lo. Block: 32 n, 128 windows, 128 couts.
// LDS: im2col [32 nloc][6 rows][160 cin] bf16, XOR-swizzled. h1 [128][NW].
// ---------------------------------------------------------------------------
#define E1_LDS (192*320)
__global__ __launch_bounds__(256) void k_enc1_gemm(
    const bf16* __restrict__ mag, const bf16* __restrict__ w1b,
    const float* __restrict__ b1, bf16* __restrict__ h1)
{
  __shared__ __align__(16) char Bs[E1_LDS];
  const int tid = threadIdx.x, lane = tid & 63, wq = tid >> 6;
  const int n0 = blockIdx.x * 32;
  const int i  = n0 >> 13, b0 = n0 & 8191;
  const size_t colbase = (size_t)i*32768 + (size_t)b0*4;

  for (int off = tid*16; off < E1_LDS; off += 256*16)
    *(f32x4*)(Bs + off) = f32x4{0.f,0.f,0.f,0.f};
  __syncthreads();
  for (int it = tid; it < 129*64; it += 256){
    const int cin = it >> 6, seg = it & 63;
    const unsigned int pair =
        *(const unsigned int*)(mag + (size_t)cin*NW + colbase + seg*2);
    #pragma unroll
    for (int q = 0; q < 2; ++q){
      const int w = seg*2 + q;
      const int row = (w>>2)*6 + (w&3) + 1;
      int off = row*320 + cin*2; off ^= ((row&7)<<4);
      *(short*)(Bs + off) = (short)((q==0) ? (pair & 0xffff) : (pair >> 16));
    }
  }
  __syncthreads();

  const int wr = wq >> 1, wc = wq & 1;
  f32x4 acc[4][4];
  #pragma unroll
  for (int mg = 0; mg < 4; ++mg)
    #pragma unroll
    for (int ng = 0; ng < 4; ++ng) acc[mg][ng] = f32x4{0.f,0.f,0.f,0.f};

  int brow[4], acol[4];
  #pragma unroll
  for (int ng = 0; ng < 4; ++ng){
    const int w = wc*64 + ng*16 + (lane & 15);
    brow[ng] = (w>>2)*6 + (w&3);
  }
  #pragma unroll
  for (int mg = 0; mg < 4; ++mg) acol[mg] = wr*64 + mg*16 + (lane & 15);
  const int kb = (lane>>4)*16;

  for (int dt = 0; dt < 3; ++dt){
    #pragma unroll
    for (int ks = 0; ks < 5; ++ks){
      short8 afrH[4], afrL[4], bfr[4];
      #pragma unroll
      for (int mg = 0; mg < 4; ++mg){
        const char* base = (const char*)w1b +
            ((dt*128 + acol[mg])*320 + ks*32)*2 + kb;
        afrH[mg] = *(const short8*)base;
        afrL[mg] = *(const short8*)(base + 320);     // +160 elements
      }
      #pragma unroll
      for (int ng = 0; ng < 4; ++ng){
        const int row = brow[ng] + dt;
        int off = row*320 + ks*64 + kb; off ^= ((row&7)<<4);
        bfr[ng] = *(const short8*)(Bs + off);
      }
      #pragma unroll
      for (int mg = 0; mg < 4; ++mg)
        #pragma unroll
        for (int ng = 0; ng < 4; ++ng){
          acc[mg][ng] = __builtin_amdgcn_mfma_f32_16x16x32_bf16(
              afrH[mg], bfr[ng], acc[mg][ng], 0, 0, 0);
          acc[mg][ng] = __builtin_amdgcn_mfma_f32_16x16x32_bf16(
              afrL[mg], bfr[ng], acc[mg][ng], 0, 0, 0);
        }
    }
  }
  #pragma unroll
  for (int mg = 0; mg < 4; ++mg)
    #pragma unroll
    for (int j = 0; j < 4; ++j){
      const int cout = wr*64 + mg*16 + (lane>>4)*4 + j;
      const float bv = b1[cout];
      #pragma unroll
      for (int ng = 0; ng < 4; ++ng){
        const int col = wc*64 + ng*16 + (lane & 15);
        float v = acc[mg][ng][j] + bv; v = v > 0.f ? v : 0.f;
        h1[(size_t)cout*NW + colbase + col] = f2b(v);
      }
    }
}

// ---------------------------------------------------------------------------
// K3: enc2 MFMA GEMM hi/lo (128->64, k=3, stride 2). h2 [64][NT2].
// ---------------------------------------------------------------------------
#define E2_LDS (160*256)
__global__ __launch_bounds__(256) void k_enc2_gemm(
    const bf16* __restrict__ h1, const bf16* __restrict__ w2b,
    const float* __restrict__ b2, bf16* __restrict__ h2)
{
  __shared__ __align__(16) char Bs[E2_LDS];
  const int tid = threadIdx.x, lane = tid & 63, wq = tid >> 6;
  const int n0 = blockIdx.x * 32;
  const int i  = n0 >> 13, b0 = n0 & 8191;
  const size_t colbase = (size_t)i*32768 + (size_t)b0*4;
  const size_t col2base = (size_t)i*16384 + (size_t)b0*2;

  for (int off = tid*16; off < E2_LDS; off += 256*16)
    *(f32x4*)(Bs + off) = f32x4{0.f,0.f,0.f,0.f};
  __syncthreads();
  for (int it = tid; it < 128*64; it += 256){
    const int cin = it >> 6, seg = it & 63;
    const unsigned int pair =
        *(const unsigned int*)(h1 + (size_t)cin*NW + colbase + seg*2);
    #pragma unroll
    for (int q = 0; q < 2; ++q){
      const int w = seg*2 + q;
      const int row = (w>>2)*5 + (w&3) + 1;
      int off = row*256 + cin*2; off ^= ((row&7)<<4);
      *(short*)(Bs + off) = (short)((q==0) ? (pair & 0xffff) : (pair >> 16));
    }
  }
  __syncthreads();

  const int wr = wq >> 1, wc = wq & 1;
  f32x4 acc[2][2];
  #pragma unroll
  for (int mg = 0; mg < 2; ++mg)
    #pragma unroll
    for (int ng = 0; ng < 2; ++ng) acc[mg][ng] = f32x4{0.f,0.f,0.f,0.f};

  int brow[2], acol[2];
  #pragma unroll
  for (int ng = 0; ng < 2; ++ng){
    const int wl = wc*32 + ng*16 + (lane & 15);
    brow[ng] = (wl>>1)*5 + (wl&1)*2;
  }
  #pragma unroll
  for (int mg = 0; mg < 2; ++mg) acol[mg] = wr*32 + mg*16 + (lane & 15);
  const int kb = (lane>>4)*16;

  for (int dt = 0; dt < 3; ++dt){
    #pragma unroll
    for (int ks = 0; ks < 4; ++ks){
      short8 afrH[2], afrL[2], bfr[2];
      #pragma unroll
      for (int mg = 0; mg < 2; ++mg){
        const char* base = (const char*)w2b +
            ((dt*64 + acol[mg])*256 + ks*32)*2 + kb;
        afrH[mg] = *(const short8*)base;
        afrL[mg] = *(const short8*)(base + 256);     // +128 elements
      }
      #pragma unroll
      for (int ng = 0; ng < 2; ++ng){
        const int row = brow[ng] + dt;
        int off = row*256 + ks*64 + kb; off ^= ((row&7)<<4);
        bfr[ng] = *(const short8*)(Bs + off);
      }
      #pragma unroll
      for (int mg = 0; mg < 2; ++mg)
        #pragma unroll
        for (int ng = 0; ng < 2; ++ng){
          acc[mg][ng] = __builtin_amdgcn_mfma_f32_16x16x32_bf16(
              afrH[mg], bfr[ng], acc[mg][ng], 0, 0, 0);
          acc[mg][ng] = __builtin_amdgcn_mfma_f32_16x16x32_bf16(
              afrL[mg], bfr[ng], acc[mg][ng], 0, 0, 0);
        }
    }
  }
  #pragma unroll
  for (int mg = 0; mg < 2; ++mg)
    #pragma unroll
    for (int j = 0; j < 4; ++j){
      const int cout = wr*32 + mg*16 + (lane>>4)*4 + j;
      const float bv = b2[cout];
      #pragma unroll
      for (int ng = 0; ng < 2; ++ng){
        const int col = wc*32 + ng*16 + (lane & 15);
        float v = acc[mg][ng][j] + bv; v = v > 0.f ? v : 0.f;
        h2[(size_t)cout*NT2 + col2base + col] = f2b(v);
      }
    }
}

// K4: enc3 (64->64, k=3, stride 2, pad 1) + ReLU, fp32 VALU. h3 [64][NTOT].
__global__ __launch_bounds__(256) void k_enc3(
    const bf16* __restrict__ h2, const float* __restrict__ w3,
    const float* __restrict__ b3v, bf16* __restrict__ h3)
{
  const int idx = blockIdx.x*256 + threadIdx.x;
  const int n  = idx & (NTOT-1);
  const int c4 = idx >> 16;            // 0..15
  const int i = n >> 13, b = n & (BATCH-1);
  const size_t cb = (size_t)i*16384 + (size_t)b*2;
  float acc[4];
  #pragma unroll
  for (int kk = 0; kk < 4; ++kk) acc[kk] = b3v[c4*4+kk];
  for (int cin = 0; cin < 64; ++cin){
    const unsigned int pair = *(const unsigned int*)(h2 + (size_t)cin*NT2 + cb);
    const float m0 = b2f(*(const bf16*)&pair);
    const bf16 hi = *((const bf16*)&pair + 1);
    const float m1 = b2f(hi);
    #pragma unroll
    for (int kk = 0; kk < 4; ++kk){
      const float* wp = w3 + ((size_t)(c4*4+kk)*64 + cin)*3;
      acc[kk] += wp[1]*m0 + wp[2]*m1;
    }
  }
  #pragma unroll
  for (int kk = 0; kk < 4; ++kk){
    float v = acc[kk]; v = v > 0.f ? v : 0.f;
    h3[(size_t)(c4*4+kk)*NTOT + n] = f2b(v);
  }
}

// K5: enc4 (64->128, center tap) + ReLU, fp32 VALU. h4 [128][NTOT].
__global__ __launch_bounds__(256) void k_enc4(
    const bf16* __restrict__ h3, const float* __restrict__ w4,
    const float* __restrict__ b4v, bf16* __restrict__ h4)
{
  const int idx = blockIdx.x*256 + threadIdx.x;
  const int n  = idx & (NTOT-1);
  const int c4 = idx >> 16;            // 0..31
  float acc[4];
  #pragma unroll
  for (int kk = 0; kk < 4; ++kk) acc[kk] = b4v[c4*4+kk];
  for (int cin = 0; cin < 64; ++cin){
    const float m = b2f(h3[(size_t)cin*NTOT + n]);
    #pragma unroll
    for (int kk = 0; kk < 4; ++kk)
      acc[kk] += w4[((size_t)(c4*4+kk)*64 + cin)*3 + 1] * m;
  }
  #pragma unroll
  for (int kk = 0; kk < 4; ++kk){
    float v = acc[kk]; v = v > 0.f ? v : 0.f;
    h4[(size_t)(c4*4+kk)*NTOT + n] = f2b(v);
  }
}

// K6: transpose h0/c0 [B,128] -> [128][B]  (LAUNCHED AFTER ENCODER — mag dead)
__global__ __launch_bounds__(256) void k_init(
    const float* __restrict__ h0, const float* __restrict__ c0,
    float* __restrict__ hT0, float* __restrict__ cT)
{
  const int idx = blockIdx.x*256 + threadIdx.x;   // 1M
  const int b = idx >> 7, c = idx & 127;
  hT0[c*BATCH + b] = h0[idx];
  cT [c*BATCH + b] = c0[idx];
}

// ---------------------------------------------------------------------------
// K7: one LSTM step, MFMA, K=640 with full first-order hi/lo terms:
// A = [Whh_hi|Whh_hi|Whh_lo|Wih_hi|Wih_lo], B rows = [h_hi; h_lo; h_hi; x; x]
// Wave wq owns c-slice [wq*32, wq*32+32) of ALL 4 gates.
// ---------------------------------------------------------------------------
__global__ __launch_bounds__(256) void k_lstm_mfma(
    const bf16* __restrict__ h4, const bf16* __restrict__ wl,
    const float* __restrict__ bih, const float* __restrict__ bhh,
    const float* __restrict__ hprev, float* __restrict__ hout,
    float* __restrict__ cT, int step)
{
  __shared__ __align__(16) char Bs[32*1280];
  const int tid = threadIdx.x, lane = tid & 63, wq = tid >> 6;
  const int b0 = blockIdx.x * 32;

  for (int it = tid; it < 128*32; it += 256){   // hprev -> hi(cp), lo(128+cp), hi(256+cp)
    const int cp = it >> 5, bl = it & 31;
    const float v = hprev[cp*BATCH + b0 + bl];
    const bf16 hi = f2b(v);
    const bf16 lo = f2b(v - b2f(hi));
    int off1 = bl*1280 + cp*2;        off1 ^= ((bl&7)<<4);
    int off2 = bl*1280 + (128+cp)*2;  off2 ^= ((bl&7)<<4);
    int off3 = bl*1280 + (256+cp)*2;  off3 ^= ((bl&7)<<4);
    *(short*)(Bs + off1) = *(const short*)&hi;
    *(short*)(Bs + off2) = *(const short*)&lo;
    *(short*)(Bs + off3) = *(const short*)&hi;
  }
  for (int it = tid; it < 128*32; it += 256){   // x -> k 384+cp and 512+cp
    const int cp = it >> 5, bl = it & 31;
    const bf16 v = h4[(size_t)cp*NTOT + step*BATCH + b0 + bl];
    int off4 = bl*1280 + (384+cp)*2;  off4 ^= ((bl&7)<<4);
    int off5 = bl*1280 + (512+cp)*2;  off5 ^= ((bl&7)<<4);
    *(short*)(Bs + off4) = *(const short*)&v;
    *(short*)(Bs + off5) = *(const short*)&v;
  }
  __syncthreads();

  const int c0 = wq*32;
  f32x4 acc[4][2][2];
  #pragma unroll
  for (int g = 0; g < 4; ++g)
    #pragma unroll
    for (int h = 0; h < 2; ++h)
      #pragma unroll
      for (int ng = 0; ng < 2; ++ng) acc[g][h][ng] = f32x4{0.f,0.f,0.f,0.f};

  int arow[4][2];
  #pragma unroll
  for (int g = 0; g < 4; ++g)
    #pragma unroll
    for (int h = 0; h < 2; ++h)
      arow[g][h] = (g*128 + c0 + h*16 + (lane&15))*1280 + (lane>>4)*16;

  #pragma unroll
  for (int ks = 0; ks < 20; ++ks){
    short8 bfr[2];
    #pragma unroll
    for (int ng = 0; ng < 2; ++ng){
      const int row = ng*16 + (lane & 15);
      int off = row*1280 + ks*64 + (lane>>4)*16; off ^= ((row&7)<<4);
      bfr[ng] = *(const short8*)(Bs + off);
    }
    #pragma unroll
    for (int g = 0; g < 4; ++g)
      #pragma unroll
      for (int h = 0; h < 2; ++h){
        const short8 a = *(const short8*)((const char*)wl + arow[g][h] + ks*64);
        #pragma unroll
        for (int ng = 0; ng < 2; ++ng)
          acc[g][h][ng] = __builtin_amdgcn_mfma_f32_16x16x32_bf16(
              a, bfr[ng], acc[g][h][ng], 0, 0, 0);
      }
  }

  #pragma unroll
  for (int h = 0; h < 2; ++h)
    #pragma unroll
    for (int ng = 0; ng < 2; ++ng)
      #pragma unroll
      for (int j = 0; j < 4; ++j){
        const int c = c0 + h*16 + (lane>>4)*4 + j;
        const int b = b0 + ng*16 + (lane & 15);
        const float ig = acc[0][h][ng][j] + bih[c]       + bhh[c];
        const float fg = acc[1][h][ng][j] + bih[128 + c] + bhh[128 + c];
        const float gg = acc[2][h][ng][j] + bih[256 + c] + bhh[256 + c];
        const float og = acc[3][h][ng][j] + bih[384 + c] + bhh[384 + c];
        const float cold = cT[c*BATCH + b];
        const float cn = sigf(fg)*cold + sigf(ig)*tanhfast(gg);
        const float hn = sigf(og)*tanhfast(cn);
        cT  [c*BATCH + b] = cn;
        hout[c*BATCH + b] = hn;
      }
}

// K8a: P[s][b] = sigmoid(ow . hseq[s][:,b] + ob)
__global__ __launch_bounds__(256) void k_headp(
    const float* __restrict__ hseq, const float* __restrict__ ow,
    const float* __restrict__ ob, float* __restrict__ P)
{
  const int idx = blockIdx.x*256 + threadIdx.x;   // 65536
  const int s = idx >> 13, b = idx & (BATCH-1);
  const float* hp = hseq + (size_t)s*HID*BATCH;
  float acc = ob[0];
  for (int c = 0; c < 128; ++c) acc += ow[c]*hp[c*BATCH + b];
  P[s*BATCH + b] = sigf(acc);
}
// K8b: final = 1 - prod(1 - P[s])
__global__ __launch_bounds__(256) void k_head2(
    const float* __restrict__ P, float* __restrict__ outp)
{
  const int b = blockIdx.x*256 + threadIdx.x;     // 8192
  float prod = 1.f;
  #pragma unroll
  for (int s = 0; s < 8; ++s) prod *= (1.f - P[s*BATCH + b]);
  outp[b] = 1.f - prod;
}

// K9: transpose h_fin, c_fin to [B,128] in d_out
__global__ __launch_bounds__(256) void k_outT(
    const float* __restrict__ h7, const float* __restrict__ cT,
    float* __restrict__ out)
{
  const int idx = blockIdx.x*256 + threadIdx.x;   // 1M
  const int b = idx >> 7, c = idx & 127;
  out[8192 + idx]           = h7[c*BATCH + b];
  out[8192 + 1048576 + idx] = cT[c*BATCH + b];
}

// ---------------------------------------------------------------------------
extern "C" void kernel_launch(void* const* d_in, const int* in_sizes, int n_in,
                              void* d_out, int out_size, void* d_ws, size_t ws_size,
                              hipStream_t stream)
{
  (void)in_sizes; (void)n_in; (void)out_size; (void)ws_size;
  const float* audio = (const float*)d_in[0];
  const float* h0    = (const float*)d_in[1];
  const float* c0    = (const float*)d_in[2];
  const float* stftw = (const float*)d_in[3];
  const float* w1 = (const float*)d_in[4];  const float* b1 = (const float*)d_in[5];
  const float* w2 = (const float*)d_in[6];  const float* b2 = (const float*)d_in[7];
  const float* w3 = (const float*)d_in[8];  const float* b3 = (const float*)d_in[9];
  const float* w4 = (const float*)d_in[10]; const float* b4 = (const float*)d_in[11];
  const float* wih = (const float*)d_in[12]; const float* whh = (const float*)d_in[13];
  const float* bih = (const float*)d_in[14]; const float* bhh = (const float*)d_in[15];
  const float* ow  = (const float*)d_in[16]; const float* ob  = (const float*)d_in[17];
  float* out = (float*)d_out;

  // Workspace schedule (write-time annotated; every placement's write happens
  // only after any overlapping buffer is dead):
  //   t1 stft:  mag   [0 .. 67,633,152)                reads Wbf
  //   t2 enc1:  h1    [67,633,152 .. 134,742,016)      reads mag, w1b
  //   t3 enc2:  h2    [134,742,016 .. 151,519,232)     reads h1, w2b
  //   t4 enc3:  h3    [0 .. 8,388,608)                 (mag dead)
  //   t5 enc4:  h4    [8,388,608 .. 25,165,824)        (mag dead)
  //   t6 init:  hT0   [25,165,824 .. 29,360,128)       (mag dead)  <-- WAS THE BUG
  //             cT    [29,360,128 .. 33,554,432)
  //   t7 lstm:  hseq  [33,554,432 .. 67,108,864)       reads wl2 (dead h1 slot)
  //   t8 head:  Pbuf  over dead hT0
  //   weights: Wbf @67,633,152 (t0, dead after t1; overwritten by h1 at t2)
  //            w1b @134,742,016 (t0, dead after t2; overwritten by h2 at t3)
  //            w2b @33,554,432 (AFTER stft, dead after t3; overwritten by hseq t7)
  //            wl2 @67,633,152 (AFTER enc2 over dead h1; live through t7)
  char* ws = (char*)d_ws;
  bf16*  mag  = (bf16*) (ws + 0);
  bf16*  h3   = (bf16*) (ws + 0);
  bf16*  h4   = (bf16*) (ws + 8388608);
  float* hT0  = (float*)(ws + 25165824);
  float* Pbuf = (float*)(ws + 25165824);
  float* cT   = (float*)(ws + 29360128);
  bf16*  w2b  = (bf16*) (ws + 33554432);
  float* hseq = (float*)(ws + 33554432);
  bf16*  h1   = (bf16*) (ws + 67633152);
  bf16*  Wbf  = (bf16*) (ws + 67633152);
  bf16*  wl2  = (bf16*) (ws + 67633152);
  bf16*  h2   = (bf16*) (ws + 134742016);
  bf16*  w1b  = (bf16*) (ws + 134742016);

  k_wcvt <<<258, 256, 0, stream>>>(stftw, Wbf);
  k_w1cvt<<<480, 256, 0, stream>>>(w1, w1b);
  k_stft_gemm<<<2048, 256, 0, stream>>>(audio, Wbf, mag);
  k_w2cvt<<<192, 256, 0, stream>>>(w2, w2b);          // after stft (mag writes done)
  k_enc1_gemm<<<2048, 256, 0, stream>>>(mag, w1b, b1, h1);
  k_enc2_gemm<<<2048, 256, 0, stream>>>(h1, w2b, b2, h2);
  k_enc3<<<4096, 256, 0, stream>>>(h2, w3, b3, h3);
  k_enc4<<<8192, 256, 0, stream>>>(h3, w4, b4, h4);
  k_wlcvt<<<1280, 256, 0, stream>>>(wih, whh, wl2);   // after enc2 (h1 dead)
  k_init <<<4096, 256, 0, stream>>>(h0, c0, hT0, cT); // after encoder (mag dead)
  for (int s = 0; s < 8; ++s){
    const float* hprev = (s == 0) ? hT0 : (hseq + (size_t)(s-1)*HID*BATCH);
    k_lstm_mfma<<<256, 256, 0, stream>>>(h4, wl2, bih, bhh, hprev,
                                         hseq + (size_t)s*HID*BATCH, cT, s);
  }
  k_headp<<<256, 256, 0, stream>>>(hseq, ow, ob, Pbuf);
  k_head2<<<32, 256, 0, stream>>>(Pbuf, out);
  k_outT<<<4096, 256, 0, stream>>>(hseq + (size_t)7*HID*BATCH, cT, out);
}